// Round 6
// baseline (1443.904 us; speedup 1.0000x reference)
//
#include <hip/hip_runtime.h>

#define THREADS 256

typedef _Float16 f16;
typedef _Float16 f16x8 __attribute__((ext_vector_type(8)));
typedef _Float16 f16x4 __attribute__((ext_vector_type(4)));
typedef float f32x4 __attribute__((ext_vector_type(4)));

// ---------------- CSR build ----------------

__global__ void k_count(const int* __restrict__ rows, int* __restrict__ cnt, int e) {
  int i = blockIdx.x * THREADS + threadIdx.x;
  if (i < e) atomicAdd(&cnt[rows[i]], 1);
}

__global__ void k_scan1(const int* __restrict__ cnt, int* __restrict__ outp,
                        int* __restrict__ bsum, int n) {
  __shared__ int sh[256];
  int t = threadIdx.x;
  int base = blockIdx.x * 1024 + t * 4;
  int v[4];
#pragma unroll
  for (int j = 0; j < 4; ++j) {
    int idx = base + j;
    v[j] = (idx < n) ? cnt[idx] : 0;
  }
  int tot = v[0] + v[1] + v[2] + v[3];
  sh[t] = tot;
  __syncthreads();
  for (int off = 1; off < 256; off <<= 1) {
    int x = 0;
    if (t >= off) x = sh[t - off];
    __syncthreads();
    sh[t] += x;
    __syncthreads();
  }
  if (t == 255) bsum[blockIdx.x] = sh[255];
  int run = sh[t] - tot;
#pragma unroll
  for (int j = 0; j < 4; ++j) {
    int idx = base + j;
    if (idx < n) outp[idx] = run;
    run += v[j];
  }
}

__global__ void k_scan2(int* __restrict__ bsum, int nb) {
  __shared__ int sh[256];
  int t = threadIdx.x;
  int v = (t < nb) ? bsum[t] : 0;
  sh[t] = v;
  __syncthreads();
  for (int off = 1; off < 256; off <<= 1) {
    int x = 0;
    if (t >= off) x = sh[t - off];
    __syncthreads();
    sh[t] += x;
    __syncthreads();
  }
  if (t < nb) bsum[t] = sh[t] - v;
}

__global__ void k_scan3(int* __restrict__ rowptr, const int* __restrict__ bsum,
                        int n, int total) {
  int base = blockIdx.x * 1024 + threadIdx.x * 4;
  int add = bsum[blockIdx.x];
#pragma unroll
  for (int j = 0; j < 4; ++j) {
    int idx = base + j;
    if (idx < n) rowptr[idx] += add;
  }
  if (blockIdx.x == 0 && threadIdx.x == 0) rowptr[n] = total;
}

// packed edge: .x = col, .y = bit-cast weight; fill pre-initialized to rowptr
__global__ void k_fill(const int* __restrict__ rows, const int* __restrict__ cols,
                       const float* __restrict__ w, int* __restrict__ fill,
                       int2* __restrict__ ed, int e) {
  int i = blockIdx.x * THREADS + threadIdx.x;
  if (i >= e) return;
  int r = rows[i];
  int p = atomicAdd(&fill[r], 1);
  ed[p] = make_int2(cols[i], __float_as_int(w[i]));
}

// ---------------- weight prep ----------------

__global__ void k_convW(const float* __restrict__ W, f16* __restrict__ Wt, int K, int N,
                        float* __restrict__ sums) {
  int i = blockIdx.x * THREADS + threadIdx.x;
  if (blockIdx.x == 0 && threadIdx.x < 256) {
    sums[threadIdx.x] = 0.f;
    sums[256 + threadIdx.x] = 0.f;
  }
  if (i >= N * K) return;
  int n = i / K, k = i - n * K;
  Wt[i] = (f16)W[(size_t)k * N + n];
}

__global__ void k_convWs(const float* __restrict__ W, const float* __restrict__ sc,
                         f16* __restrict__ Wt, int K, int N, float* __restrict__ sums) {
  int i = blockIdx.x * THREADS + threadIdx.x;
  if (blockIdx.x == 0 && threadIdx.x < 256) {
    sums[threadIdx.x] = 0.f;
    sums[256 + threadIdx.x] = 0.f;
  }
  if (i >= N * K) return;
  int n = i / K, k = i - n * K;
  Wt[i] = (f16)(sc[k] * W[(size_t)k * N + n]);
}

__global__ void k_biasfold(const float* __restrict__ sf, const float* __restrict__ W,
                           float* __restrict__ biasRow, int K, int N) {
  int n = threadIdx.x;
  if (n >= N) return;
  int k0 = blockIdx.x * 16;
  float s = 0.f;
#pragma unroll
  for (int i = 0; i < 16; ++i) {
    int k = k0 + i;
    s += sf[k] * W[(size_t)k * N + n];
  }
  atomicAdd(&biasRow[n], s);
}

// ---------------- MFMA GEMM: Csup[M][BN] = A[M][K] @ Wt^T + biasRow, f16 out ----
// BM=128 rows per block, 256 threads (4 waves).

template <int BN, bool AF16>
__global__ __launch_bounds__(256) void k_gemm_mfma(
    const void* __restrict__ Ap, const f16* __restrict__ Wt,
    const float* __restrict__ biasRow, f16* __restrict__ Csup, int M, int K) {
  constexpr int BM = 128;
  constexpr int BK = 32;
  constexpr int LDT = BK + 8;
  __shared__ __align__(16) f16 As[BM][LDT];
  __shared__ __align__(16) f16 Bs[BN][LDT];

  const int tid = threadIdx.x;
  const int wave = tid >> 6;
  const int lane = tid & 63;
  const int m0 = blockIdx.x * BM;
  constexpr int WM = (BN == 256) ? 8 : 2;
  constexpr int WN = 4;
  const int wrow = (BN == 256) ? 0 : wave * 32;
  const int wcol = (BN == 256) ? wave * 64 : 0;
  const int l15 = lane & 15;
  const int lq = lane >> 4;

  const int arow = tid >> 1;
  const int akofs = (tid & 1) * 16;
  const int srow = tid >> 2;
  const int skofs = (tid & 3) * 8;
  constexpr int BROWS = BN / 64;

  f32x4 acc[WM][WN] = {};

  for (int k0 = 0; k0 < K; k0 += BK) {
    f16x8 a16[2];
    int gr = m0 + arow;
    if constexpr (AF16) {
      if (gr < M) {
        const f16* ap = (const f16*)Ap + (size_t)gr * K + k0 + akofs;
        a16[0] = *(const f16x8*)ap;
        a16[1] = *(const f16x8*)(ap + 8);
      } else {
#pragma unroll
        for (int j = 0; j < 8; ++j) { a16[0][j] = (f16)0.f; a16[1][j] = (f16)0.f; }
      }
    } else {
      float va[16];
      if (gr < M) {
        const float* ap = (const float*)Ap + (size_t)gr * K + k0 + akofs;
#pragma unroll
        for (int q = 0; q < 4; ++q) *(float4*)&va[q * 4] = *(const float4*)(ap + q * 4);
      } else {
#pragma unroll
        for (int j = 0; j < 16; ++j) va[j] = 0.f;
      }
#pragma unroll
      for (int j = 0; j < 8; ++j) { a16[0][j] = (f16)va[j]; a16[1][j] = (f16)va[8 + j]; }
    }

    f16x8 vb[BROWS];
#pragma unroll
    for (int j = 0; j < BROWS; ++j)
      vb[j] = *(const f16x8*)(Wt + (size_t)(srow + j * 64) * K + k0 + skofs);

    __syncthreads();
    *(f16x8*)&As[arow][akofs] = a16[0];
    *(f16x8*)&As[arow][akofs + 8] = a16[1];
#pragma unroll
    for (int j = 0; j < BROWS; ++j) *(f16x8*)&Bs[srow + j * 64][skofs] = vb[j];
    __syncthreads();

    f16x8 af[WM], bf[WN];
#pragma unroll
    for (int m = 0; m < WM; ++m)
      af[m] = *(const f16x8*)&As[wrow + m * 16 + l15][lq * 8];
#pragma unroll
    for (int n = 0; n < WN; ++n)
      bf[n] = *(const f16x8*)&Bs[wcol + n * 16 + l15][lq * 8];
#pragma unroll
    for (int m = 0; m < WM; ++m)
#pragma unroll
      for (int n = 0; n < WN; ++n)
        acc[m][n] = __builtin_amdgcn_mfma_f32_16x16x32_f16(af[m], bf[n], acc[m][n], 0, 0, 0);
  }

  float bb[WN];
#pragma unroll
  for (int n = 0; n < WN; ++n)
    bb[n] = biasRow ? biasRow[wcol + n * 16 + l15] : 0.f;

#pragma unroll
  for (int m = 0; m < WM; ++m) {
#pragma unroll
    for (int r = 0; r < 4; ++r) {
      int row = m0 + wrow + m * 16 + lq * 4 + r;
      if (row < M) {
        f16* cp = Csup + (size_t)row * BN + wcol + l15;
#pragma unroll
        for (int n = 0; n < WN; ++n) cp[n * 16] = (f16)(acc[m][n][r] + bb[n]);
      }
    }
  }
}

// ---------------- Aggregation D=256: one BLOCK per row, 4 waves split the edges ----
// wave q processes edge chunk q; LDS combine; 256-thread epilogue.

__global__ __launch_bounds__(256) void k_agg256(
    const f16* __restrict__ sup, const int* __restrict__ rowptr,
    const int2* __restrict__ ed, const float* __restrict__ bias,
    f16* __restrict__ out, int n) {
  __shared__ float sh[4][256];
  int r = blockIdx.x;
  int q = threadIdx.x >> 6;
  int lane = threadIdx.x & 63;
  int p0 = rowptr[r], p1 = rowptr[r + 1];
  int len = p1 - p0;
  int ps = p0 + ((len * q) >> 2);
  int pe = p0 + ((len * (q + 1)) >> 2);

  const f16x4* supv = (const f16x4*)sup;
  float acc[4][4] = {};
  int p = ps;
  for (; p + 8 <= pe; p += 8) {
    int2 e[8];
#pragma unroll
    for (int j = 0; j < 8; ++j) e[j] = ed[p + j];
    f16x4 v[8];
#pragma unroll
    for (int j = 0; j < 8; ++j) v[j] = supv[(size_t)e[j].x * 64 + lane];
#pragma unroll
    for (int j = 0; j < 8; ++j) {
      float wt = __int_as_float(e[j].y);
      acc[j & 3][0] += wt * (float)v[j][0];
      acc[j & 3][1] += wt * (float)v[j][1];
      acc[j & 3][2] += wt * (float)v[j][2];
      acc[j & 3][3] += wt * (float)v[j][3];
    }
  }
  for (; p < pe; ++p) {
    int2 e0 = ed[p];
    float wt = __int_as_float(e0.y);
    f16x4 v = supv[(size_t)e0.x * 64 + lane];
    acc[0][0] += wt * (float)v[0];
    acc[0][1] += wt * (float)v[1];
    acc[0][2] += wt * (float)v[2];
    acc[0][3] += wt * (float)v[3];
  }
  float4 asum;
  asum.x = acc[0][0] + acc[1][0] + acc[2][0] + acc[3][0];
  asum.y = acc[0][1] + acc[1][1] + acc[2][1] + acc[3][1];
  asum.z = acc[0][2] + acc[1][2] + acc[2][2] + acc[3][2];
  asum.w = acc[0][3] + acc[1][3] + acc[2][3] + acc[3][3];
  *(float4*)&sh[q][lane * 4] = asum;
  __syncthreads();
  int t = threadIdx.x;
  float tot = sh[0][t] + sh[1][t] + sh[2][t] + sh[3][t] + bias[t];
  out[(size_t)r * 256 + t] = (f16)fmaxf(tot, 0.f);
}

// ---------------- Aggregation D=64: one BLOCK per row, 4 waves split the edges ----

__global__ __launch_bounds__(256) void k_agg64(
    const f16* __restrict__ sup, const int* __restrict__ rowptr,
    const int2* __restrict__ ed, const float* __restrict__ bias,
    float* __restrict__ out, int n) {
  __shared__ float sh[4][64];
  int r = blockIdx.x;
  int q = threadIdx.x >> 6;
  int lane = threadIdx.x & 63;
  int p0 = rowptr[r], p1 = rowptr[r + 1];
  int len = p1 - p0;
  int ps = p0 + ((len * q) >> 2);
  int pe = p0 + ((len * (q + 1)) >> 2);

  float acc[2] = {};
  int p = ps;
  for (; p + 8 <= pe; p += 8) {
    int2 e[8];
#pragma unroll
    for (int j = 0; j < 8; ++j) e[j] = ed[p + j];
    f16 v[8];
#pragma unroll
    for (int j = 0; j < 8; ++j) v[j] = sup[(size_t)e[j].x * 64 + lane];
#pragma unroll
    for (int j = 0; j < 8; ++j)
      acc[j & 1] += __int_as_float(e[j].y) * (float)v[j];
  }
  for (; p < pe; ++p) {
    int2 e0 = ed[p];
    acc[0] += __int_as_float(e0.y) * (float)sup[(size_t)e0.x * 64 + lane];
  }
  sh[q][lane] = acc[0] + acc[1];
  __syncthreads();
  if (threadIdx.x < 64) {
    float tot = sh[0][lane] + sh[1][lane] + sh[2][lane] + sh[3][lane] + bias[lane];
    out[(size_t)r * 64 + lane] = fmaxf(tot, 0.f);
  }
}

// ---------------- BN stats ----------------

__global__ __launch_bounds__(256) void k_colstats(const f16* __restrict__ y,
                                                  float* __restrict__ sums, int n) {
  __shared__ float sh[8][256];
  int t = threadIdx.x;
  int cg = (t & 31) * 8;
  int rs = t >> 5;
  float s[8] = {}, s2[8] = {};
  for (int r = blockIdx.x * 8 + rs; r < n; r += gridDim.x * 8) {
    f16x8 v = *(const f16x8*)(y + (size_t)r * 256 + cg);
#pragma unroll
    for (int j = 0; j < 8; ++j) {
      float f = (float)v[j];
      s[j] += f;
      s2[j] += f * f;
    }
  }
#pragma unroll
  for (int j = 0; j < 8; ++j) sh[rs][cg + j] = s[j];
  __syncthreads();
  float tot = 0.f;
#pragma unroll
  for (int k = 0; k < 8; ++k) tot += sh[k][t];
  atomicAdd(&sums[t], tot);
  __syncthreads();
#pragma unroll
  for (int j = 0; j < 8; ++j) sh[rs][cg + j] = s2[j];
  __syncthreads();
  tot = 0.f;
#pragma unroll
  for (int k = 0; k < 8; ++k) tot += sh[k][t];
  atomicAdd(&sums[256 + t], tot);
}

__global__ void k_bnparam(const float* __restrict__ sums, float* __restrict__ scale,
                          float* __restrict__ shift, float* __restrict__ biasRow, int n) {
  int c = threadIdx.x;
  float inv = 1.0f / (float)n;
  float mean = sums[c] * inv;
  float var = sums[256 + c] * inv - mean * mean;
  float rstd = rsqrtf(var + 1e-5f);
  scale[c] = rstd;
  shift[c] = -mean * rstd;
  biasRow[c] = 0.f;
}

// ---------------- launch ----------------

extern "C" void kernel_launch(void* const* d_in, const int* in_sizes, int n_in,
                              void* d_out, int out_size, void* d_ws, size_t ws_size,
                              hipStream_t stream) {
  const float* x = (const float*)d_in[0];
  const int* ei = (const int*)d_in[1];
  const float* ew = (const float*)d_in[2];
  const float* W1 = (const float*)d_in[3];
  const float* b1 = (const float*)d_in[4];
  const float* W2 = (const float*)d_in[5];
  const float* b2 = (const float*)d_in[6];
  const float* W3 = (const float*)d_in[7];
  const float* b3 = (const float*)d_in[8];
  float* out = (float*)d_out;

  const int N = in_sizes[0] / 512;  // 100000
  const int E = in_sizes[2];        // 3200000

  char* p = (char*)d_ws;
  auto alloc = [&](size_t bytes) {
    void* r = (void*)p;
    p += (bytes + 255) & ~(size_t)255;
    return r;
  };
  int* rowptr = (int*)alloc((size_t)(N + 1) * 4);
  int* cnt = (int*)alloc((size_t)N * 4);
  int* fill = (int*)alloc((size_t)N * 4);
  int* bsum = (int*)alloc(4096);
  float* sums = (float*)alloc(512 * 4);
  float* scale = (float*)alloc(256 * 4);
  float* shift = (float*)alloc(256 * 4);
  float* biasRow = (float*)alloc(256 * 4);
  f16* Wt1 = (f16*)alloc((size_t)512 * 256 * 2);
  f16* Wt2 = (f16*)alloc((size_t)256 * 256 * 2);
  f16* Wt3 = (f16*)alloc((size_t)256 * 64 * 2);
  int2* ed = (int2*)alloc((size_t)E * 8);
  f16* sup = (f16*)alloc((size_t)N * 256 * 2);
  f16* act = (f16*)alloc((size_t)N * 256 * 2);

  const int* rows = ei;
  const int* colsIn = ei + E;

  // --- CSR build ---
  hipMemsetAsync(cnt, 0, (size_t)N * 4, stream);
  k_count<<<(E + THREADS - 1) / THREADS, THREADS, 0, stream>>>(rows, cnt, E);
  int nb = (N + 1023) / 1024;
  k_scan1<<<nb, 256, 0, stream>>>(cnt, rowptr, bsum, N);
  k_scan2<<<1, 256, 0, stream>>>(bsum, nb);
  k_scan3<<<nb, 256, 0, stream>>>(rowptr, bsum, N, E);
  hipMemcpyAsync(fill, rowptr, (size_t)N * 4, hipMemcpyDeviceToDevice, stream);
  k_fill<<<(E + THREADS - 1) / THREADS, THREADS, 0, stream>>>(
      rows, colsIn, ew, fill, ed, E);

  const int gemmBlocks = (N + 127) / 128;

  // --- Layer 1 ---
  k_convW<<<(512 * 256 + THREADS - 1) / THREADS, THREADS, 0, stream>>>(W1, Wt1, 512, 256, sums);
  k_gemm_mfma<256, false><<<gemmBlocks, 256, 0, stream>>>(x, Wt1, nullptr, sup, N, 512);
  k_agg256<<<N, 256, 0, stream>>>(sup, rowptr, ed, b1, act, N);

  // --- BN1 + fold into W2 ---
  k_colstats<<<120, 256, 0, stream>>>(act, sums, N);
  k_bnparam<<<1, 256, 0, stream>>>(sums, scale, shift, biasRow, N);
  k_biasfold<<<16, 256, 0, stream>>>(shift, W2, biasRow, 256, 256);
  k_convWs<<<(256 * 256 + THREADS - 1) / THREADS, THREADS, 0, stream>>>(W2, scale, Wt2, 256, 256, sums);

  // --- Layer 2 ---
  k_gemm_mfma<256, true><<<gemmBlocks, 256, 0, stream>>>(act, Wt2, biasRow, sup, N, 256);
  k_agg256<<<N, 256, 0, stream>>>(sup, rowptr, ed, b2, act, N);

  // --- BN2 + fold into W3 ---
  k_colstats<<<120, 256, 0, stream>>>(act, sums, N);
  k_bnparam<<<1, 256, 0, stream>>>(sums, scale, shift, biasRow, N);
  k_biasfold<<<16, 256, 0, stream>>>(shift, W3, biasRow, 256, 64);
  k_convWs<<<(256 * 64 + THREADS - 1) / THREADS, THREADS, 0, stream>>>(W3, scale, Wt3, 256, 64, sums);

  // --- Layer 3 ---
  k_gemm_mfma<64, true><<<gemmBlocks, 256, 0, stream>>>(act, Wt3, biasRow, sup, N, 256);
  k_agg64<<<N, 256, 0, stream>>>(sup, rowptr, ed, b3, out, N);
}

// Round 7
// 1192.617 us; speedup vs baseline: 1.2107x; 1.2107x over previous
//
#include <hip/hip_runtime.h>

#define THREADS 256

typedef _Float16 f16;
typedef _Float16 f16x8 __attribute__((ext_vector_type(8)));
typedef _Float16 f16x4 __attribute__((ext_vector_type(4)));
typedef float f32x4 __attribute__((ext_vector_type(4)));

// ---------------- CSR build ----------------

__global__ void k_count(const int* __restrict__ rows, int* __restrict__ cnt, int e) {
  int i = blockIdx.x * THREADS + threadIdx.x;
  if (i < e) atomicAdd(&cnt[rows[i]], 1);
}

__global__ void k_scan1(const int* __restrict__ cnt, int* __restrict__ outp,
                        int* __restrict__ bsum, int n) {
  __shared__ int sh[256];
  int t = threadIdx.x;
  int base = blockIdx.x * 1024 + t * 4;
  int v[4];
#pragma unroll
  for (int j = 0; j < 4; ++j) {
    int idx = base + j;
    v[j] = (idx < n) ? cnt[idx] : 0;
  }
  int tot = v[0] + v[1] + v[2] + v[3];
  sh[t] = tot;
  __syncthreads();
  for (int off = 1; off < 256; off <<= 1) {
    int x = 0;
    if (t >= off) x = sh[t - off];
    __syncthreads();
    sh[t] += x;
    __syncthreads();
  }
  if (t == 255) bsum[blockIdx.x] = sh[255];
  int run = sh[t] - tot;
#pragma unroll
  for (int j = 0; j < 4; ++j) {
    int idx = base + j;
    if (idx < n) outp[idx] = run;
    run += v[j];
  }
}

__global__ void k_scan2(int* __restrict__ bsum, int nb) {
  __shared__ int sh[256];
  int t = threadIdx.x;
  int v = (t < nb) ? bsum[t] : 0;
  sh[t] = v;
  __syncthreads();
  for (int off = 1; off < 256; off <<= 1) {
    int x = 0;
    if (t >= off) x = sh[t - off];
    __syncthreads();
    sh[t] += x;
    __syncthreads();
  }
  if (t < nb) bsum[t] = sh[t] - v;
}

__global__ void k_scan3(int* __restrict__ rowptr, const int* __restrict__ bsum,
                        int n, int total) {
  int base = blockIdx.x * 1024 + threadIdx.x * 4;
  int add = bsum[blockIdx.x];
#pragma unroll
  for (int j = 0; j < 4; ++j) {
    int idx = base + j;
    if (idx < n) rowptr[idx] += add;
  }
  if (blockIdx.x == 0 && threadIdx.x == 0) rowptr[n] = total;
}

// packed edge: .x = col, .y = bit-cast weight; fill pre-initialized to rowptr
__global__ void k_fill(const int* __restrict__ rows, const int* __restrict__ cols,
                       const float* __restrict__ w, int* __restrict__ fill,
                       int2* __restrict__ ed, int e) {
  int i = blockIdx.x * THREADS + threadIdx.x;
  if (i >= e) return;
  int r = rows[i];
  int p = atomicAdd(&fill[r], 1);
  ed[p] = make_int2(cols[i], __float_as_int(w[i]));
}

// ---------------- weight prep ----------------

__global__ void k_convW(const float* __restrict__ W, f16* __restrict__ Wt, int K, int N,
                        float* __restrict__ sums) {
  int i = blockIdx.x * THREADS + threadIdx.x;
  if (blockIdx.x == 0 && threadIdx.x < 256) {
    sums[threadIdx.x] = 0.f;
    sums[256 + threadIdx.x] = 0.f;
  }
  if (i >= N * K) return;
  int n = i / K, k = i - n * K;
  Wt[i] = (f16)W[(size_t)k * N + n];
}

__global__ void k_convWs(const float* __restrict__ W, const float* __restrict__ sc,
                         f16* __restrict__ Wt, int K, int N, float* __restrict__ sums) {
  int i = blockIdx.x * THREADS + threadIdx.x;
  if (blockIdx.x == 0 && threadIdx.x < 256) {
    sums[threadIdx.x] = 0.f;
    sums[256 + threadIdx.x] = 0.f;
  }
  if (i >= N * K) return;
  int n = i / K, k = i - n * K;
  Wt[i] = (f16)(sc[k] * W[(size_t)k * N + n]);
}

__global__ void k_biasfold(const float* __restrict__ sf, const float* __restrict__ W,
                           float* __restrict__ biasRow, int K, int N) {
  int n = threadIdx.x;
  if (n >= N) return;
  int k0 = blockIdx.x * 16;
  float s = 0.f;
#pragma unroll
  for (int i = 0; i < 16; ++i) {
    int k = k0 + i;
    s += sf[k] * W[(size_t)k * N + n];
  }
  atomicAdd(&biasRow[n], s);
}

// ---------------- MFMA GEMM: Csup[M][BN] = A[M][K] @ Wt^T + biasRow, f16 out ----
// BM=128 rows per block, 256 threads (4 waves).

template <int BN, bool AF16>
__global__ __launch_bounds__(256) void k_gemm_mfma(
    const void* __restrict__ Ap, const f16* __restrict__ Wt,
    const float* __restrict__ biasRow, f16* __restrict__ Csup, int M, int K) {
  constexpr int BM = 128;
  constexpr int BK = 32;
  constexpr int LDT = BK + 8;
  __shared__ __align__(16) f16 As[BM][LDT];
  __shared__ __align__(16) f16 Bs[BN][LDT];

  const int tid = threadIdx.x;
  const int wave = tid >> 6;
  const int lane = tid & 63;
  const int m0 = blockIdx.x * BM;
  constexpr int WM = (BN == 256) ? 8 : 2;
  constexpr int WN = 4;
  const int wrow = (BN == 256) ? 0 : wave * 32;
  const int wcol = (BN == 256) ? wave * 64 : 0;
  const int l15 = lane & 15;
  const int lq = lane >> 4;

  const int arow = tid >> 1;
  const int akofs = (tid & 1) * 16;
  const int srow = tid >> 2;
  const int skofs = (tid & 3) * 8;
  constexpr int BROWS = BN / 64;

  f32x4 acc[WM][WN] = {};

  for (int k0 = 0; k0 < K; k0 += BK) {
    f16x8 a16[2];
    int gr = m0 + arow;
    if constexpr (AF16) {
      if (gr < M) {
        const f16* ap = (const f16*)Ap + (size_t)gr * K + k0 + akofs;
        a16[0] = *(const f16x8*)ap;
        a16[1] = *(const f16x8*)(ap + 8);
      } else {
#pragma unroll
        for (int j = 0; j < 8; ++j) { a16[0][j] = (f16)0.f; a16[1][j] = (f16)0.f; }
      }
    } else {
      float va[16];
      if (gr < M) {
        const float* ap = (const float*)Ap + (size_t)gr * K + k0 + akofs;
#pragma unroll
        for (int q = 0; q < 4; ++q) *(float4*)&va[q * 4] = *(const float4*)(ap + q * 4);
      } else {
#pragma unroll
        for (int j = 0; j < 16; ++j) va[j] = 0.f;
      }
#pragma unroll
      for (int j = 0; j < 8; ++j) { a16[0][j] = (f16)va[j]; a16[1][j] = (f16)va[8 + j]; }
    }

    f16x8 vb[BROWS];
#pragma unroll
    for (int j = 0; j < BROWS; ++j)
      vb[j] = *(const f16x8*)(Wt + (size_t)(srow + j * 64) * K + k0 + skofs);

    __syncthreads();
    *(f16x8*)&As[arow][akofs] = a16[0];
    *(f16x8*)&As[arow][akofs + 8] = a16[1];
#pragma unroll
    for (int j = 0; j < BROWS; ++j) *(f16x8*)&Bs[srow + j * 64][skofs] = vb[j];
    __syncthreads();

    f16x8 af[WM], bf[WN];
#pragma unroll
    for (int m = 0; m < WM; ++m)
      af[m] = *(const f16x8*)&As[wrow + m * 16 + l15][lq * 8];
#pragma unroll
    for (int n = 0; n < WN; ++n)
      bf[n] = *(const f16x8*)&Bs[wcol + n * 16 + l15][lq * 8];
#pragma unroll
    for (int m = 0; m < WM; ++m)
#pragma unroll
      for (int n = 0; n < WN; ++n)
        acc[m][n] = __builtin_amdgcn_mfma_f32_16x16x32_f16(af[m], bf[n], acc[m][n], 0, 0, 0);
  }

  float bb[WN];
#pragma unroll
  for (int n = 0; n < WN; ++n)
    bb[n] = biasRow ? biasRow[wcol + n * 16 + l15] : 0.f;

#pragma unroll
  for (int m = 0; m < WM; ++m) {
#pragma unroll
    for (int r = 0; r < 4; ++r) {
      int row = m0 + wrow + m * 16 + lq * 4 + r;
      if (row < M) {
        f16* cp = Csup + (size_t)row * BN + wcol + l15;
#pragma unroll
        for (int n = 0; n < WN; ++n) cp[n * 16] = (f16)(acc[m][n][r] + bb[n]);
      }
    }
  }
}

// ---------------- Aggregation D=256: one WAVE per row, 16-deep gather pipeline ----

__global__ __launch_bounds__(256) void k_agg256(
    const f16* __restrict__ sup, const int* __restrict__ rowptr,
    const int2* __restrict__ ed, const float* __restrict__ bias,
    f16* __restrict__ out, int n) {
  int wid = (blockIdx.x * THREADS + threadIdx.x) >> 6;
  int lane = threadIdx.x & 63;
  if (wid >= n) return;
  int p0 = rowptr[wid], p1 = rowptr[wid + 1];

  const f16x4* supv = (const f16x4*)sup;
  float acc[4][4] = {};
  int p = p0;
  for (; p + 16 <= p1; p += 16) {
    int2 e[16];
#pragma unroll
    for (int j = 0; j < 16; ++j) e[j] = ed[p + j];
    f16x4 v[16];
#pragma unroll
    for (int j = 0; j < 16; ++j) v[j] = supv[(size_t)e[j].x * 64 + lane];
#pragma unroll
    for (int j = 0; j < 16; ++j) {
      float wt = __int_as_float(e[j].y);
      acc[j & 3][0] += wt * (float)v[j][0];
      acc[j & 3][1] += wt * (float)v[j][1];
      acc[j & 3][2] += wt * (float)v[j][2];
      acc[j & 3][3] += wt * (float)v[j][3];
    }
  }
  for (; p + 4 <= p1; p += 4) {
    int2 e[4];
#pragma unroll
    for (int j = 0; j < 4; ++j) e[j] = ed[p + j];
    f16x4 v[4];
#pragma unroll
    for (int j = 0; j < 4; ++j) v[j] = supv[(size_t)e[j].x * 64 + lane];
#pragma unroll
    for (int j = 0; j < 4; ++j) {
      float wt = __int_as_float(e[j].y);
      acc[j][0] += wt * (float)v[j][0];
      acc[j][1] += wt * (float)v[j][1];
      acc[j][2] += wt * (float)v[j][2];
      acc[j][3] += wt * (float)v[j][3];
    }
  }
  for (; p < p1; ++p) {
    int2 e0 = ed[p];
    float wt = __int_as_float(e0.y);
    f16x4 v = supv[(size_t)e0.x * 64 + lane];
    acc[0][0] += wt * (float)v[0];
    acc[0][1] += wt * (float)v[1];
    acc[0][2] += wt * (float)v[2];
    acc[0][3] += wt * (float)v[3];
  }
  float4 b = *(const float4*)(bias + lane * 4);
  f16x4 r;
  r[0] = (f16)fmaxf(acc[0][0] + acc[1][0] + acc[2][0] + acc[3][0] + b.x, 0.f);
  r[1] = (f16)fmaxf(acc[0][1] + acc[1][1] + acc[2][1] + acc[3][1] + b.y, 0.f);
  r[2] = (f16)fmaxf(acc[0][2] + acc[1][2] + acc[2][2] + acc[3][2] + b.z, 0.f);
  r[3] = (f16)fmaxf(acc[0][3] + acc[1][3] + acc[2][3] + acc[3][3] + b.w, 0.f);
  *(f16x4*)(out + (size_t)wid * 256 + lane * 4) = r;
}

// ---------------- Aggregation D=64: one WAVE per row (lane = feature), 16-deep ----

__global__ __launch_bounds__(256) void k_agg64(
    const f16* __restrict__ sup, const int* __restrict__ rowptr,
    const int2* __restrict__ ed, const float* __restrict__ bias,
    float* __restrict__ out, int n) {
  int wid = (blockIdx.x * THREADS + threadIdx.x) >> 6;
  int lane = threadIdx.x & 63;
  if (wid >= n) return;
  int p0 = rowptr[wid], p1 = rowptr[wid + 1];

  float acc[4] = {};
  int p = p0;
  for (; p + 16 <= p1; p += 16) {
    int2 e[16];
#pragma unroll
    for (int j = 0; j < 16; ++j) e[j] = ed[p + j];
    f16 v[16];
#pragma unroll
    for (int j = 0; j < 16; ++j) v[j] = sup[(size_t)e[j].x * 64 + lane];
#pragma unroll
    for (int j = 0; j < 16; ++j)
      acc[j & 3] += __int_as_float(e[j].y) * (float)v[j];
  }
  for (; p + 4 <= p1; p += 4) {
    int2 e[4];
#pragma unroll
    for (int j = 0; j < 4; ++j) e[j] = ed[p + j];
    f16 v[4];
#pragma unroll
    for (int j = 0; j < 4; ++j) v[j] = sup[(size_t)e[j].x * 64 + lane];
#pragma unroll
    for (int j = 0; j < 4; ++j)
      acc[j] += __int_as_float(e[j].y) * (float)v[j];
  }
  for (; p < p1; ++p) {
    int2 e0 = ed[p];
    acc[0] += __int_as_float(e0.y) * (float)sup[(size_t)e0.x * 64 + lane];
  }
  out[(size_t)wid * 64 + lane] =
      fmaxf(acc[0] + acc[1] + acc[2] + acc[3] + bias[lane], 0.f);
}

// ---------------- BN stats ----------------

__global__ __launch_bounds__(256) void k_colstats(const f16* __restrict__ y,
                                                  float* __restrict__ sums, int n) {
  __shared__ float sh[8][256];
  int t = threadIdx.x;
  int cg = (t & 31) * 8;
  int rs = t >> 5;
  float s[8] = {}, s2[8] = {};
  for (int r = blockIdx.x * 8 + rs; r < n; r += gridDim.x * 8) {
    f16x8 v = *(const f16x8*)(y + (size_t)r * 256 + cg);
#pragma unroll
    for (int j = 0; j < 8; ++j) {
      float f = (float)v[j];
      s[j] += f;
      s2[j] += f * f;
    }
  }
#pragma unroll
  for (int j = 0; j < 8; ++j) sh[rs][cg + j] = s[j];
  __syncthreads();
  float tot = 0.f;
#pragma unroll
  for (int k = 0; k < 8; ++k) tot += sh[k][t];
  atomicAdd(&sums[t], tot);
  __syncthreads();
#pragma unroll
  for (int j = 0; j < 8; ++j) sh[rs][cg + j] = s2[j];
  __syncthreads();
  tot = 0.f;
#pragma unroll
  for (int k = 0; k < 8; ++k) tot += sh[k][t];
  atomicAdd(&sums[256 + t], tot);
}

__global__ void k_bnparam(const float* __restrict__ sums, float* __restrict__ scale,
                          float* __restrict__ shift, float* __restrict__ biasRow, int n) {
  int c = threadIdx.x;
  float inv = 1.0f / (float)n;
  float mean = sums[c] * inv;
  float var = sums[256 + c] * inv - mean * mean;
  float rstd = rsqrtf(var + 1e-5f);
  scale[c] = rstd;
  shift[c] = -mean * rstd;
  biasRow[c] = 0.f;
}

// ---------------- launch ----------------

extern "C" void kernel_launch(void* const* d_in, const int* in_sizes, int n_in,
                              void* d_out, int out_size, void* d_ws, size_t ws_size,
                              hipStream_t stream) {
  const float* x = (const float*)d_in[0];
  const int* ei = (const int*)d_in[1];
  const float* ew = (const float*)d_in[2];
  const float* W1 = (const float*)d_in[3];
  const float* b1 = (const float*)d_in[4];
  const float* W2 = (const float*)d_in[5];
  const float* b2 = (const float*)d_in[6];
  const float* W3 = (const float*)d_in[7];
  const float* b3 = (const float*)d_in[8];
  float* out = (float*)d_out;

  const int N = in_sizes[0] / 512;  // 100000
  const int E = in_sizes[2];        // 3200000

  char* p = (char*)d_ws;
  auto alloc = [&](size_t bytes) {
    void* r = (void*)p;
    p += (bytes + 255) & ~(size_t)255;
    return r;
  };
  int* rowptr = (int*)alloc((size_t)(N + 1) * 4);
  int* cnt = (int*)alloc((size_t)N * 4);
  int* fill = (int*)alloc((size_t)N * 4);
  int* bsum = (int*)alloc(4096);
  float* sums = (float*)alloc(512 * 4);
  float* scale = (float*)alloc(256 * 4);
  float* shift = (float*)alloc(256 * 4);
  float* biasRow = (float*)alloc(256 * 4);
  f16* Wt1 = (f16*)alloc((size_t)512 * 256 * 2);
  f16* Wt2 = (f16*)alloc((size_t)256 * 256 * 2);
  f16* Wt3 = (f16*)alloc((size_t)256 * 64 * 2);
  int2* ed = (int2*)alloc((size_t)E * 8);
  f16* sup = (f16*)alloc((size_t)N * 256 * 2);
  f16* act = (f16*)alloc((size_t)N * 256 * 2);

  const int* rows = ei;
  const int* colsIn = ei + E;

  // --- CSR build ---
  hipMemsetAsync(cnt, 0, (size_t)N * 4, stream);
  k_count<<<(E + THREADS - 1) / THREADS, THREADS, 0, stream>>>(rows, cnt, E);
  int nb = (N + 1023) / 1024;
  k_scan1<<<nb, 256, 0, stream>>>(cnt, rowptr, bsum, N);
  k_scan2<<<1, 256, 0, stream>>>(bsum, nb);
  k_scan3<<<nb, 256, 0, stream>>>(rowptr, bsum, N, E);
  hipMemcpyAsync(fill, rowptr, (size_t)N * 4, hipMemcpyDeviceToDevice, stream);
  k_fill<<<(E + THREADS - 1) / THREADS, THREADS, 0, stream>>>(
      rows, colsIn, ew, fill, ed, E);

  const int gemmBlocks = (N + 127) / 128;
  const int aggBlocks = (N * 64 + THREADS - 1) / THREADS;

  // --- Layer 1 ---
  k_convW<<<(512 * 256 + THREADS - 1) / THREADS, THREADS, 0, stream>>>(W1, Wt1, 512, 256, sums);
  k_gemm_mfma<256, false><<<gemmBlocks, 256, 0, stream>>>(x, Wt1, nullptr, sup, N, 512);
  k_agg256<<<aggBlocks, 256, 0, stream>>>(sup, rowptr, ed, b1, act, N);

  // --- BN1 + fold into W2 ---
  k_colstats<<<120, 256, 0, stream>>>(act, sums, N);
  k_bnparam<<<1, 256, 0, stream>>>(sums, scale, shift, biasRow, N);
  k_biasfold<<<16, 256, 0, stream>>>(shift, W2, biasRow, 256, 256);
  k_convWs<<<(256 * 256 + THREADS - 1) / THREADS, THREADS, 0, stream>>>(W2, scale, Wt2, 256, 256, sums);

  // --- Layer 2 ---
  k_gemm_mfma<256, true><<<gemmBlocks, 256, 0, stream>>>(act, Wt2, biasRow, sup, N, 256);
  k_agg256<<<aggBlocks, 256, 0, stream>>>(sup, rowptr, ed, b2, act, N);

  // --- BN2 + fold into W3 ---
  k_colstats<<<120, 256, 0, stream>>>(act, sums, N);
  k_bnparam<<<1, 256, 0, stream>>>(sums, scale, shift, biasRow, N);
  k_biasfold<<<16, 256, 0, stream>>>(shift, W3, biasRow, 256, 64);
  k_convWs<<<(256 * 64 + THREADS - 1) / THREADS, THREADS, 0, stream>>>(W3, scale, Wt3, 256, 64, sums);

  // --- Layer 3 ---
  k_gemm_mfma<64, true><<<gemmBlocks, 256, 0, stream>>>(act, Wt3, biasRow, sup, N, 256);
  k_agg64<<<aggBlocks, 256, 0, stream>>>(sup, rowptr, ed, b3, out, N);
}

// Round 8
// 923.256 us; speedup vs baseline: 1.5639x; 1.2918x over previous
//
#include <hip/hip_runtime.h>

#define THREADS 256
#define BSH 8        // rows per bucket = 256
#define EPB 8192     // edges per binning block (256 threads x 32)

typedef _Float16 f16;
typedef _Float16 f16x8 __attribute__((ext_vector_type(8)));
typedef _Float16 f16x4 __attribute__((ext_vector_type(4)));
typedef float f32x4 __attribute__((ext_vector_type(4)));

// ---------------- generic scan (1024 elems/block) ----------------

__global__ void k_scan1(const int* __restrict__ cnt, int* __restrict__ outp,
                        int* __restrict__ bsum, int n) {
  __shared__ int sh[256];
  int t = threadIdx.x;
  int base = blockIdx.x * 1024 + t * 4;
  int v[4];
#pragma unroll
  for (int j = 0; j < 4; ++j) {
    int idx = base + j;
    v[j] = (idx < n) ? cnt[idx] : 0;
  }
  int tot = v[0] + v[1] + v[2] + v[3];
  sh[t] = tot;
  __syncthreads();
  for (int off = 1; off < 256; off <<= 1) {
    int x = 0;
    if (t >= off) x = sh[t - off];
    __syncthreads();
    sh[t] += x;
    __syncthreads();
  }
  if (t == 255) bsum[blockIdx.x] = sh[255];
  int run = sh[t] - tot;
#pragma unroll
  for (int j = 0; j < 4; ++j) {
    int idx = base + j;
    if (idx < n) outp[idx] = run;
    run += v[j];
  }
}

__global__ void k_scan2(int* __restrict__ bsum, int nb) {
  __shared__ int sh[256];
  int t = threadIdx.x;
  int v = (t < nb) ? bsum[t] : 0;
  sh[t] = v;
  __syncthreads();
  for (int off = 1; off < 256; off <<= 1) {
    int x = 0;
    if (t >= off) x = sh[t - off];
    __syncthreads();
    sh[t] += x;
    __syncthreads();
  }
  if (t < nb) bsum[t] = sh[t] - v;
}

__global__ void k_scan3(int* __restrict__ outp, const int* __restrict__ bsum,
                        int n, int total) {
  int base = blockIdx.x * 1024 + threadIdx.x * 4;
  int add = bsum[blockIdx.x];
#pragma unroll
  for (int j = 0; j < 4; ++j) {
    int idx = base + j;
    if (idx < n) outp[idx] += add;
  }
  if (blockIdx.x == 0 && threadIdx.x == 0) outp[n] = total;
}

// ---------------- CSR build: atomic-free two-level binning ----------------

// A1: per-(bucket, block) histogram. cnt2d[b * nblk + blk]
__global__ __launch_bounds__(256) void k_hist(const int* __restrict__ rows,
                                              int* __restrict__ cnt2d,
                                              int e, int nblk, int nb) {
  __shared__ int hist[512];
  int blk = blockIdx.x, t = threadIdx.x;
  for (int i = t; i < nb; i += 256) hist[i] = 0;
  __syncthreads();
  int eb = blk * EPB;
#pragma unroll 4
  for (int it = 0; it < 32; ++it) {
    int i = eb + it * 256 + t;
    if (i < e) atomicAdd(&hist[rows[i] >> BSH], 1);
  }
  __syncthreads();
  for (int i = t; i < nb; i += 256) cnt2d[i * nblk + blk] = hist[i];
}

// A2: place packed edges at exact offsets (dense bucket-major temp). No global atomics.
__global__ __launch_bounds__(256) void k_bin(
    const int* __restrict__ rows, const int* __restrict__ cols,
    const float* __restrict__ w, const int* __restrict__ off2d,
    int2* __restrict__ temp, int e, int nblk, int nb) {
  __shared__ int base[512];
  __shared__ int cursor[512];
  int blk = blockIdx.x, t = threadIdx.x;
  for (int i = t; i < nb; i += 256) {
    base[i] = off2d[i * nblk + blk];
    cursor[i] = 0;
  }
  __syncthreads();
  int eb = blk * EPB;
#pragma unroll 4
  for (int it = 0; it < 32; ++it) {
    int i = eb + it * 256 + t;
    if (i < e) {
      int r = rows[i];
      int b = r >> BSH;
      int pos = base[b] + atomicAdd(&cursor[b], 1);
      // pack: rowOffset (8b) << 17 | col (17b); weight bits in .y
      temp[pos] = make_int2(((r & 255) << 17) | cols[i], __float_as_int(w[i]));
    }
  }
}

// B: one block per bucket. Derives rowptr (LDS scan) and scatters edges into the
// bucket's L2-resident CSR window.
__global__ __launch_bounds__(256) void k_scatter(
    const int2* __restrict__ temp, const int* __restrict__ off2d,
    int* __restrict__ rowptr, int2* __restrict__ ed,
    int n, int e, int nblk, int nb) {
  __shared__ int rowCnt[256];
  __shared__ int rowBase[256];
  __shared__ int rowCur[256];
  int b = blockIdx.x, t = threadIdx.x;
  int r0 = b << BSH;
  int nr = min(256, n - r0);
  int start = off2d[b * nblk];
  int end = off2d[(b + 1) * nblk];  // off2d[nb*nblk] == e for the last bucket
  rowCnt[t] = 0;
  __syncthreads();
  for (int p = start + t; p < end; p += 256)
    atomicAdd(&rowCnt[temp[p].x >> 17], 1);
  __syncthreads();
  int v = rowCnt[t];
  rowBase[t] = v;
  __syncthreads();
  for (int off = 1; off < 256; off <<= 1) {
    int x = 0;
    if (t >= off) x = rowBase[t - off];
    __syncthreads();
    rowBase[t] += x;
    __syncthreads();
  }
  int excl = rowBase[t] - v;
  __syncthreads();
  rowBase[t] = excl;
  rowCur[t] = 0;
  if (t < nr) rowptr[r0 + t] = start + excl;
  if (b == nb - 1 && t == 0) rowptr[n] = e;
  __syncthreads();
  for (int p = start + t; p < end; p += 256) {
    int2 ei = temp[p];
    int ro = ei.x >> 17;
    int slot = start + rowBase[ro] + atomicAdd(&rowCur[ro], 1);
    ed[slot] = make_int2(ei.x & 0x1FFFF, ei.y);
  }
}

// ---------------- weight prep ----------------

__global__ void k_convW(const float* __restrict__ W, f16* __restrict__ Wt, int K, int N,
                        float* __restrict__ sums) {
  int i = blockIdx.x * THREADS + threadIdx.x;
  if (blockIdx.x == 0 && threadIdx.x < 256) {
    sums[threadIdx.x] = 0.f;
    sums[256 + threadIdx.x] = 0.f;
  }
  if (i >= N * K) return;
  int n = i / K, k = i - n * K;
  Wt[i] = (f16)W[(size_t)k * N + n];
}

__global__ void k_convWs(const float* __restrict__ W, const float* __restrict__ sc,
                         f16* __restrict__ Wt, int K, int N, float* __restrict__ sums) {
  int i = blockIdx.x * THREADS + threadIdx.x;
  if (blockIdx.x == 0 && threadIdx.x < 256) {
    sums[threadIdx.x] = 0.f;
    sums[256 + threadIdx.x] = 0.f;
  }
  if (i >= N * K) return;
  int n = i / K, k = i - n * K;
  Wt[i] = (f16)(sc[k] * W[(size_t)k * N + n]);
}

__global__ void k_biasfold(const float* __restrict__ sf, const float* __restrict__ W,
                           float* __restrict__ biasRow, int K, int N) {
  int n = threadIdx.x;
  if (n >= N) return;
  int k0 = blockIdx.x * 16;
  float s = 0.f;
#pragma unroll
  for (int i = 0; i < 16; ++i) {
    int k = k0 + i;
    s += sf[k] * W[(size_t)k * N + n];
  }
  atomicAdd(&biasRow[n], s);
}

// ---------------- MFMA GEMM: Csup[M][BN] = A[M][K] @ Wt^T + biasRow, f16 out ----

template <int BN, bool AF16>
__global__ __launch_bounds__(256) void k_gemm_mfma(
    const void* __restrict__ Ap, const f16* __restrict__ Wt,
    const float* __restrict__ biasRow, f16* __restrict__ Csup, int M, int K) {
  constexpr int BM = 128;
  constexpr int BK = 32;
  constexpr int LDT = BK + 8;
  __shared__ __align__(16) f16 As[BM][LDT];
  __shared__ __align__(16) f16 Bs[BN][LDT];

  const int tid = threadIdx.x;
  const int wave = tid >> 6;
  const int lane = tid & 63;
  const int m0 = blockIdx.x * BM;
  constexpr int WM = (BN == 256) ? 8 : 2;
  constexpr int WN = 4;
  const int wrow = (BN == 256) ? 0 : wave * 32;
  const int wcol = (BN == 256) ? wave * 64 : 0;
  const int l15 = lane & 15;
  const int lq = lane >> 4;

  const int arow = tid >> 1;
  const int akofs = (tid & 1) * 16;
  const int srow = tid >> 2;
  const int skofs = (tid & 3) * 8;
  constexpr int BROWS = BN / 64;

  f32x4 acc[WM][WN] = {};

  for (int k0 = 0; k0 < K; k0 += BK) {
    f16x8 a16[2];
    int gr = m0 + arow;
    if constexpr (AF16) {
      if (gr < M) {
        const f16* ap = (const f16*)Ap + (size_t)gr * K + k0 + akofs;
        a16[0] = *(const f16x8*)ap;
        a16[1] = *(const f16x8*)(ap + 8);
      } else {
#pragma unroll
        for (int j = 0; j < 8; ++j) { a16[0][j] = (f16)0.f; a16[1][j] = (f16)0.f; }
      }
    } else {
      float va[16];
      if (gr < M) {
        const float* ap = (const float*)Ap + (size_t)gr * K + k0 + akofs;
#pragma unroll
        for (int q = 0; q < 4; ++q) *(float4*)&va[q * 4] = *(const float4*)(ap + q * 4);
      } else {
#pragma unroll
        for (int j = 0; j < 16; ++j) va[j] = 0.f;
      }
#pragma unroll
      for (int j = 0; j < 8; ++j) { a16[0][j] = (f16)va[j]; a16[1][j] = (f16)va[8 + j]; }
    }

    f16x8 vb[BROWS];
#pragma unroll
    for (int j = 0; j < BROWS; ++j)
      vb[j] = *(const f16x8*)(Wt + (size_t)(srow + j * 64) * K + k0 + skofs);

    __syncthreads();
    *(f16x8*)&As[arow][akofs] = a16[0];
    *(f16x8*)&As[arow][akofs + 8] = a16[1];
#pragma unroll
    for (int j = 0; j < BROWS; ++j) *(f16x8*)&Bs[srow + j * 64][skofs] = vb[j];
    __syncthreads();

    f16x8 af[WM], bf[WN];
#pragma unroll
    for (int m = 0; m < WM; ++m)
      af[m] = *(const f16x8*)&As[wrow + m * 16 + l15][lq * 8];
#pragma unroll
    for (int n = 0; n < WN; ++n)
      bf[n] = *(const f16x8*)&Bs[wcol + n * 16 + l15][lq * 8];
#pragma unroll
    for (int m = 0; m < WM; ++m)
#pragma unroll
      for (int n = 0; n < WN; ++n)
        acc[m][n] = __builtin_amdgcn_mfma_f32_16x16x32_f16(af[m], bf[n], acc[m][n], 0, 0, 0);
  }

  float bb[WN];
#pragma unroll
  for (int n = 0; n < WN; ++n)
    bb[n] = biasRow ? biasRow[wcol + n * 16 + l15] : 0.f;

#pragma unroll
  for (int m = 0; m < WM; ++m) {
#pragma unroll
    for (int r = 0; r < 4; ++r) {
      int row = m0 + wrow + m * 16 + lq * 4 + r;
      if (row < M) {
        f16* cp = Csup + (size_t)row * BN + wcol + l15;
#pragma unroll
        for (int n = 0; n < WN; ++n) cp[n * 16] = (f16)(acc[m][n][r] + bb[n]);
      }
    }
  }
}

// ---------------- Aggregation D=256: one WAVE per row, 16-deep gather pipeline ----

__global__ __launch_bounds__(256) void k_agg256(
    const f16* __restrict__ sup, const int* __restrict__ rowptr,
    const int2* __restrict__ ed, const float* __restrict__ bias,
    f16* __restrict__ out, int n) {
  int wid = (blockIdx.x * THREADS + threadIdx.x) >> 6;
  int lane = threadIdx.x & 63;
  if (wid >= n) return;
  int p0 = rowptr[wid], p1 = rowptr[wid + 1];

  const f16x4* supv = (const f16x4*)sup;
  float acc[4][4] = {};
  int p = p0;
  for (; p + 16 <= p1; p += 16) {
    int2 e[16];
#pragma unroll
    for (int j = 0; j < 16; ++j) e[j] = ed[p + j];
    f16x4 v[16];
#pragma unroll
    for (int j = 0; j < 16; ++j) v[j] = supv[(size_t)e[j].x * 64 + lane];
#pragma unroll
    for (int j = 0; j < 16; ++j) {
      float wt = __int_as_float(e[j].y);
      acc[j & 3][0] += wt * (float)v[j][0];
      acc[j & 3][1] += wt * (float)v[j][1];
      acc[j & 3][2] += wt * (float)v[j][2];
      acc[j & 3][3] += wt * (float)v[j][3];
    }
  }
  for (; p + 4 <= p1; p += 4) {
    int2 e[4];
#pragma unroll
    for (int j = 0; j < 4; ++j) e[j] = ed[p + j];
    f16x4 v[4];
#pragma unroll
    for (int j = 0; j < 4; ++j) v[j] = supv[(size_t)e[j].x * 64 + lane];
#pragma unroll
    for (int j = 0; j < 4; ++j) {
      float wt = __int_as_float(e[j].y);
      acc[j][0] += wt * (float)v[j][0];
      acc[j][1] += wt * (float)v[j][1];
      acc[j][2] += wt * (float)v[j][2];
      acc[j][3] += wt * (float)v[j][3];
    }
  }
  for (; p < p1; ++p) {
    int2 e0 = ed[p];
    float wt = __int_as_float(e0.y);
    f16x4 v = supv[(size_t)e0.x * 64 + lane];
    acc[0][0] += wt * (float)v[0];
    acc[0][1] += wt * (float)v[1];
    acc[0][2] += wt * (float)v[2];
    acc[0][3] += wt * (float)v[3];
  }
  float4 b = *(const float4*)(bias + lane * 4);
  f16x4 r;
  r[0] = (f16)fmaxf(acc[0][0] + acc[1][0] + acc[2][0] + acc[3][0] + b.x, 0.f);
  r[1] = (f16)fmaxf(acc[0][1] + acc[1][1] + acc[2][1] + acc[3][1] + b.y, 0.f);
  r[2] = (f16)fmaxf(acc[0][2] + acc[1][2] + acc[2][2] + acc[3][2] + b.z, 0.f);
  r[3] = (f16)fmaxf(acc[0][3] + acc[1][3] + acc[2][3] + acc[3][3] + b.w, 0.f);
  *(f16x4*)(out + (size_t)wid * 256 + lane * 4) = r;
}

// ---------------- Aggregation D=64: one WAVE per row (lane = feature), 16-deep ----

__global__ __launch_bounds__(256) void k_agg64(
    const f16* __restrict__ sup, const int* __restrict__ rowptr,
    const int2* __restrict__ ed, const float* __restrict__ bias,
    float* __restrict__ out, int n) {
  int wid = (blockIdx.x * THREADS + threadIdx.x) >> 6;
  int lane = threadIdx.x & 63;
  if (wid >= n) return;
  int p0 = rowptr[wid], p1 = rowptr[wid + 1];

  float acc[4] = {};
  int p = p0;
  for (; p + 16 <= p1; p += 16) {
    int2 e[16];
#pragma unroll
    for (int j = 0; j < 16; ++j) e[j] = ed[p + j];
    f16 v[16];
#pragma unroll
    for (int j = 0; j < 16; ++j) v[j] = sup[(size_t)e[j].x * 64 + lane];
#pragma unroll
    for (int j = 0; j < 16; ++j)
      acc[j & 3] += __int_as_float(e[j].y) * (float)v[j];
  }
  for (; p + 4 <= p1; p += 4) {
    int2 e[4];
#pragma unroll
    for (int j = 0; j < 4; ++j) e[j] = ed[p + j];
    f16 v[4];
#pragma unroll
    for (int j = 0; j < 4; ++j) v[j] = sup[(size_t)e[j].x * 64 + lane];
#pragma unroll
    for (int j = 0; j < 4; ++j)
      acc[j] += __int_as_float(e[j].y) * (float)v[j];
  }
  for (; p < p1; ++p) {
    int2 e0 = ed[p];
    acc[0] += __int_as_float(e0.y) * (float)sup[(size_t)e0.x * 64 + lane];
  }
  out[(size_t)wid * 64 + lane] =
      fmaxf(acc[0] + acc[1] + acc[2] + acc[3] + bias[lane], 0.f);
}

// ---------------- BN stats ----------------

__global__ __launch_bounds__(256) void k_colstats(const f16* __restrict__ y,
                                                  float* __restrict__ sums, int n) {
  __shared__ float sh[8][256];
  int t = threadIdx.x;
  int cg = (t & 31) * 8;
  int rs = t >> 5;
  float s[8] = {}, s2[8] = {};
  for (int r = blockIdx.x * 8 + rs; r < n; r += gridDim.x * 8) {
    f16x8 v = *(const f16x8*)(y + (size_t)r * 256 + cg);
#pragma unroll
    for (int j = 0; j < 8; ++j) {
      float f = (float)v[j];
      s[j] += f;
      s2[j] += f * f;
    }
  }
#pragma unroll
  for (int j = 0; j < 8; ++j) sh[rs][cg + j] = s[j];
  __syncthreads();
  float tot = 0.f;
#pragma unroll
  for (int k = 0; k < 8; ++k) tot += sh[k][t];
  atomicAdd(&sums[t], tot);
  __syncthreads();
#pragma unroll
  for (int j = 0; j < 8; ++j) sh[rs][cg + j] = s2[j];
  __syncthreads();
  tot = 0.f;
#pragma unroll
  for (int k = 0; k < 8; ++k) tot += sh[k][t];
  atomicAdd(&sums[256 + t], tot);
}

__global__ void k_bnparam(const float* __restrict__ sums, float* __restrict__ scale,
                          float* __restrict__ shift, float* __restrict__ biasRow, int n) {
  int c = threadIdx.x;
  float inv = 1.0f / (float)n;
  float mean = sums[c] * inv;
  float var = sums[256 + c] * inv - mean * mean;
  float rstd = rsqrtf(var + 1e-5f);
  scale[c] = rstd;
  shift[c] = -mean * rstd;
  biasRow[c] = 0.f;
}

// ---------------- launch ----------------

extern "C" void kernel_launch(void* const* d_in, const int* in_sizes, int n_in,
                              void* d_out, int out_size, void* d_ws, size_t ws_size,
                              hipStream_t stream) {
  const float* x = (const float*)d_in[0];
  const int* ei = (const int*)d_in[1];
  const float* ew = (const float*)d_in[2];
  const float* W1 = (const float*)d_in[3];
  const float* b1 = (const float*)d_in[4];
  const float* W2 = (const float*)d_in[5];
  const float* b2 = (const float*)d_in[6];
  const float* W3 = (const float*)d_in[7];
  const float* b3 = (const float*)d_in[8];
  float* out = (float*)d_out;

  const int N = in_sizes[0] / 512;  // 100000
  const int E = in_sizes[2];        // 3200000

  const int NB = (N + 255) >> BSH;            // buckets (391)
  const int NBLK = (E + EPB - 1) / EPB;       // binning blocks (391)
  const int scanN = NB * NBLK;

  char* p = (char*)d_ws;
  auto alloc = [&](size_t bytes) {
    void* r = (void*)p;
    p += (bytes + 255) & ~(size_t)255;
    return r;
  };
  int* rowptr = (int*)alloc((size_t)(N + 1) * 4);
  int* cnt2d = (int*)alloc((size_t)scanN * 4);
  int* off2d = (int*)alloc((size_t)(scanN + 1) * 4);
  int* bsum = (int*)alloc(4096);
  float* sums = (float*)alloc(512 * 4);
  float* scale = (float*)alloc(256 * 4);
  float* shift = (float*)alloc(256 * 4);
  float* biasRow = (float*)alloc(256 * 4);
  f16* Wt1 = (f16*)alloc((size_t)512 * 256 * 2);
  f16* Wt2 = (f16*)alloc((size_t)256 * 256 * 2);
  f16* Wt3 = (f16*)alloc((size_t)256 * 64 * 2);
  int2* temp = (int2*)alloc((size_t)E * 8);
  int2* ed = (int2*)alloc((size_t)E * 8);
  f16* sup = (f16*)alloc((size_t)N * 256 * 2);
  f16* act = (f16*)alloc((size_t)N * 256 * 2);

  const int* rows = ei;
  const int* colsIn = ei + E;

  // --- CSR build (atomic-free binning) ---
  k_hist<<<NBLK, 256, 0, stream>>>(rows, cnt2d, E, NBLK, NB);
  int nbs = (scanN + 1023) / 1024;
  k_scan1<<<nbs, 256, 0, stream>>>(cnt2d, off2d, bsum, scanN);
  k_scan2<<<1, 256, 0, stream>>>(bsum, nbs);
  k_scan3<<<nbs, 256, 0, stream>>>(off2d, bsum, scanN, E);
  k_bin<<<NBLK, 256, 0, stream>>>(rows, colsIn, ew, off2d, temp, E, NBLK, NB);
  k_scatter<<<NB, 256, 0, stream>>>(temp, off2d, rowptr, ed, N, E, NBLK, NB);

  const int gemmBlocks = (N + 127) / 128;
  const int aggBlocks = (N * 64 + THREADS - 1) / THREADS;

  // --- Layer 1 ---
  k_convW<<<(512 * 256 + THREADS - 1) / THREADS, THREADS, 0, stream>>>(W1, Wt1, 512, 256, sums);
  k_gemm_mfma<256, false><<<gemmBlocks, 256, 0, stream>>>(x, Wt1, nullptr, sup, N, 512);
  k_agg256<<<aggBlocks, 256, 0, stream>>>(sup, rowptr, ed, b1, act, N);

  // --- BN1 + fold into W2 ---
  k_colstats<<<120, 256, 0, stream>>>(act, sums, N);
  k_bnparam<<<1, 256, 0, stream>>>(sums, scale, shift, biasRow, N);
  k_biasfold<<<16, 256, 0, stream>>>(shift, W2, biasRow, 256, 256);
  k_convWs<<<(256 * 256 + THREADS - 1) / THREADS, THREADS, 0, stream>>>(W2, scale, Wt2, 256, 256, sums);

  // --- Layer 2 ---
  k_gemm_mfma<256, true><<<gemmBlocks, 256, 0, stream>>>(act, Wt2, biasRow, sup, N, 256);
  k_agg256<<<aggBlocks, 256, 0, stream>>>(sup, rowptr, ed, b2, act, N);

  // --- BN2 + fold into W3 ---
  k_colstats<<<120, 256, 0, stream>>>(act, sums, N);
  k_bnparam<<<1, 256, 0, stream>>>(sums, scale, shift, biasRow, N);
  k_biasfold<<<16, 256, 0, stream>>>(shift, W3, biasRow, 256, 64);
  k_convWs<<<(256 * 64 + THREADS - 1) / THREADS, THREADS, 0, stream>>>(W3, scale, Wt3, 256, 64, sums);

  // --- Layer 3 ---
  k_gemm_mfma<64, true><<<gemmBlocks, 256, 0, stream>>>(act, Wt3, biasRow, sup, N, 256);
  k_agg64<<<aggBlocks, 256, 0, stream>>>(sup, rowptr, ed, b3, out, N);
}

// Round 9
// 883.778 us; speedup vs baseline: 1.6338x; 1.0447x over previous
//
#include <hip/hip_runtime.h>

#define THREADS 256
#define BSH 8        // rows per bucket = 256
#define EPB 8192     // edges per binning block (256 threads x 32)

typedef _Float16 f16;
typedef _Float16 f16x8 __attribute__((ext_vector_type(8)));
typedef _Float16 f16x4 __attribute__((ext_vector_type(4)));
typedef _Float16 f16x2 __attribute__((ext_vector_type(2)));
typedef float f32x4 __attribute__((ext_vector_type(4)));

// ---------------- generic scan (1024 elems/block) ----------------

__global__ void k_scan1(const int* __restrict__ cnt, int* __restrict__ outp,
                        int* __restrict__ bsum, int n) {
  __shared__ int sh[256];
  int t = threadIdx.x;
  int base = blockIdx.x * 1024 + t * 4;
  int v[4];
#pragma unroll
  for (int j = 0; j < 4; ++j) {
    int idx = base + j;
    v[j] = (idx < n) ? cnt[idx] : 0;
  }
  int tot = v[0] + v[1] + v[2] + v[3];
  sh[t] = tot;
  __syncthreads();
  for (int off = 1; off < 256; off <<= 1) {
    int x = 0;
    if (t >= off) x = sh[t - off];
    __syncthreads();
    sh[t] += x;
    __syncthreads();
  }
  if (t == 255) bsum[blockIdx.x] = sh[255];
  int run = sh[t] - tot;
#pragma unroll
  for (int j = 0; j < 4; ++j) {
    int idx = base + j;
    if (idx < n) outp[idx] = run;
    run += v[j];
  }
}

__global__ void k_scan2(int* __restrict__ bsum, int nb) {
  __shared__ int sh[256];
  int t = threadIdx.x;
  int v = (t < nb) ? bsum[t] : 0;
  sh[t] = v;
  __syncthreads();
  for (int off = 1; off < 256; off <<= 1) {
    int x = 0;
    if (t >= off) x = sh[t - off];
    __syncthreads();
    sh[t] += x;
    __syncthreads();
  }
  if (t < nb) bsum[t] = sh[t] - v;
}

__global__ void k_scan3(int* __restrict__ outp, const int* __restrict__ bsum,
                        int n, int total) {
  int base = blockIdx.x * 1024 + threadIdx.x * 4;
  int add = bsum[blockIdx.x];
#pragma unroll
  for (int j = 0; j < 4; ++j) {
    int idx = base + j;
    if (idx < n) outp[idx] += add;
  }
  if (blockIdx.x == 0 && threadIdx.x == 0) outp[n] = total;
}

// ---------------- CSR build: atomic-free two-level binning ----------------

__global__ __launch_bounds__(256) void k_hist(const int* __restrict__ rows,
                                              int* __restrict__ cnt2d,
                                              int e, int nblk, int nb) {
  __shared__ int hist[512];
  int blk = blockIdx.x, t = threadIdx.x;
  for (int i = t; i < nb; i += 256) hist[i] = 0;
  __syncthreads();
  int eb = blk * EPB;
#pragma unroll 4
  for (int it = 0; it < 32; ++it) {
    int i = eb + it * 256 + t;
    if (i < e) atomicAdd(&hist[rows[i] >> BSH], 1);
  }
  __syncthreads();
  for (int i = t; i < nb; i += 256) cnt2d[i * nblk + blk] = hist[i];
}

__global__ __launch_bounds__(256) void k_bin(
    const int* __restrict__ rows, const int* __restrict__ cols,
    const float* __restrict__ w, const int* __restrict__ off2d,
    int2* __restrict__ temp, int e, int nblk, int nb) {
  __shared__ int base[512];
  __shared__ int cursor[512];
  int blk = blockIdx.x, t = threadIdx.x;
  for (int i = t; i < nb; i += 256) {
    base[i] = off2d[i * nblk + blk];
    cursor[i] = 0;
  }
  __syncthreads();
  int eb = blk * EPB;
#pragma unroll 4
  for (int it = 0; it < 32; ++it) {
    int i = eb + it * 256 + t;
    if (i < e) {
      int r = rows[i];
      int b = r >> BSH;
      int pos = base[b] + atomicAdd(&cursor[b], 1);
      temp[pos] = make_int2(((r & 255) << 17) | cols[i], __float_as_int(w[i]));
    }
  }
}

__global__ __launch_bounds__(256) void k_scatter(
    const int2* __restrict__ temp, const int* __restrict__ off2d,
    int* __restrict__ rowptr, int2* __restrict__ ed,
    int n, int e, int nblk, int nb) {
  __shared__ int rowCnt[256];
  __shared__ int rowBase[256];
  __shared__ int rowCur[256];
  int b = blockIdx.x, t = threadIdx.x;
  int r0 = b << BSH;
  int nr = min(256, n - r0);
  int start = off2d[b * nblk];
  int end = off2d[(b + 1) * nblk];
  rowCnt[t] = 0;
  __syncthreads();
  for (int p = start + t; p < end; p += 256)
    atomicAdd(&rowCnt[temp[p].x >> 17], 1);
  __syncthreads();
  int v = rowCnt[t];
  rowBase[t] = v;
  __syncthreads();
  for (int off = 1; off < 256; off <<= 1) {
    int x = 0;
    if (t >= off) x = rowBase[t - off];
    __syncthreads();
    rowBase[t] += x;
    __syncthreads();
  }
  int excl = rowBase[t] - v;
  __syncthreads();
  rowBase[t] = excl;
  rowCur[t] = 0;
  if (t < nr) rowptr[r0 + t] = start + excl;
  if (b == nb - 1 && t == 0) rowptr[n] = e;
  __syncthreads();
  for (int p = start + t; p < end; p += 256) {
    int2 ei = temp[p];
    int ro = ei.x >> 17;
    int slot = start + rowBase[ro] + atomicAdd(&rowCur[ro], 1);
    ed[slot] = make_int2(ei.x & 0x1FFFF, ei.y);
  }
}

// ---------------- weight prep ----------------

// Layer-1 W transpose/convert; also zeroes both stat buffers + both biasRows
__global__ void k_convW(const float* __restrict__ W, f16* __restrict__ Wt, int K, int N,
                        float* __restrict__ statZero) {
  int i = blockIdx.x * THREADS + threadIdx.x;
  if (blockIdx.x == 0) {
#pragma unroll
    for (int j = 0; j < 6; ++j) statZero[j * 256 + threadIdx.x] = 0.f;
  }
  if (i >= N * K) return;
  int n = i / K, k = i - n * K;
  Wt[i] = (f16)W[(size_t)k * N + n];
}

// Fused BN-param + W-fold + bias-fold. Every block derives scale/shift from sums
// (redundant, cheap); first K/16 blocks also accumulate biasRow.
__global__ __launch_bounds__(256) void k_bnfold(
    const float* __restrict__ W, const float* __restrict__ sums,
    f16* __restrict__ Wt, float* __restrict__ biasRow, int K, int N, int n) {
  __shared__ float sc[256], sf[256];
  int t = threadIdx.x;
  if (t < K) {
    float inv = 1.0f / (float)n;
    float mean = sums[t] * inv;
    float var = sums[256 + t] * inv - mean * mean;
    float rstd = rsqrtf(var + 1e-5f);
    sc[t] = rstd;
    sf[t] = -mean * rstd;
  }
  __syncthreads();
  int i = blockIdx.x * 256 + t;
  if (i < N * K) {
    int nn = i / K, k = i - nn * K;
    Wt[i] = (f16)(sc[k] * W[(size_t)k * N + nn]);
  }
  if (blockIdx.x < (K >> 4) && t < N) {
    int k0 = blockIdx.x * 16;
    float s = 0.f;
#pragma unroll
    for (int j = 0; j < 16; ++j) s += sf[k0 + j] * W[(size_t)(k0 + j) * N + t];
    atomicAdd(&biasRow[t], s);
  }
}

// ---------------- MFMA GEMM: Csup[M][BN] = A[M][K] @ Wt^T + biasRow, f16 out ----

template <int BN, bool AF16>
__global__ __launch_bounds__(256) void k_gemm_mfma(
    const void* __restrict__ Ap, const f16* __restrict__ Wt,
    const float* __restrict__ biasRow, f16* __restrict__ Csup, int M, int K) {
  constexpr int BM = 128;
  constexpr int BK = 32;
  constexpr int LDT = BK + 8;
  __shared__ __align__(16) f16 As[BM][LDT];
  __shared__ __align__(16) f16 Bs[BN][LDT];

  const int tid = threadIdx.x;
  const int wave = tid >> 6;
  const int lane = tid & 63;
  const int m0 = blockIdx.x * BM;
  constexpr int WM = (BN == 256) ? 8 : 2;
  constexpr int WN = 4;
  const int wrow = (BN == 256) ? 0 : wave * 32;
  const int wcol = (BN == 256) ? wave * 64 : 0;
  const int l15 = lane & 15;
  const int lq = lane >> 4;

  const int arow = tid >> 1;
  const int akofs = (tid & 1) * 16;
  const int srow = tid >> 2;
  const int skofs = (tid & 3) * 8;
  constexpr int BROWS = BN / 64;

  f32x4 acc[WM][WN] = {};

  for (int k0 = 0; k0 < K; k0 += BK) {
    f16x8 a16[2];
    int gr = m0 + arow;
    if constexpr (AF16) {
      if (gr < M) {
        const f16* ap = (const f16*)Ap + (size_t)gr * K + k0 + akofs;
        a16[0] = *(const f16x8*)ap;
        a16[1] = *(const f16x8*)(ap + 8);
      } else {
#pragma unroll
        for (int j = 0; j < 8; ++j) { a16[0][j] = (f16)0.f; a16[1][j] = (f16)0.f; }
      }
    } else {
      float va[16];
      if (gr < M) {
        const float* ap = (const float*)Ap + (size_t)gr * K + k0 + akofs;
#pragma unroll
        for (int q = 0; q < 4; ++q) *(float4*)&va[q * 4] = *(const float4*)(ap + q * 4);
      } else {
#pragma unroll
        for (int j = 0; j < 16; ++j) va[j] = 0.f;
      }
#pragma unroll
      for (int j = 0; j < 8; ++j) { a16[0][j] = (f16)va[j]; a16[1][j] = (f16)va[8 + j]; }
    }

    f16x8 vb[BROWS];
#pragma unroll
    for (int j = 0; j < BROWS; ++j)
      vb[j] = *(const f16x8*)(Wt + (size_t)(srow + j * 64) * K + k0 + skofs);

    __syncthreads();
    *(f16x8*)&As[arow][akofs] = a16[0];
    *(f16x8*)&As[arow][akofs + 8] = a16[1];
#pragma unroll
    for (int j = 0; j < BROWS; ++j) *(f16x8*)&Bs[srow + j * 64][skofs] = vb[j];
    __syncthreads();

    f16x8 af[WM], bf[WN];
#pragma unroll
    for (int m = 0; m < WM; ++m)
      af[m] = *(const f16x8*)&As[wrow + m * 16 + l15][lq * 8];
#pragma unroll
    for (int n = 0; n < WN; ++n)
      bf[n] = *(const f16x8*)&Bs[wcol + n * 16 + l15][lq * 8];
#pragma unroll
    for (int m = 0; m < WM; ++m)
#pragma unroll
      for (int n = 0; n < WN; ++n)
        acc[m][n] = __builtin_amdgcn_mfma_f32_16x16x32_f16(af[m], bf[n], acc[m][n], 0, 0, 0);
  }

  float bb[WN];
#pragma unroll
  for (int n = 0; n < WN; ++n)
    bb[n] = biasRow ? biasRow[wcol + n * 16 + l15] : 0.f;

#pragma unroll
  for (int m = 0; m < WM; ++m) {
#pragma unroll
    for (int r = 0; r < 4; ++r) {
      int row = m0 + wrow + m * 16 + lq * 4 + r;
      if (row < M) {
        f16* cp = Csup + (size_t)row * BN + wcol + l15;
#pragma unroll
        for (int n = 0; n < WN; ++n) cp[n * 16] = (f16)(acc[m][n][r] + bb[n]);
      }
    }
  }
}

// ---------------- Aggregation D=256: one WAVE per row, 16-deep gather pipeline ----

__global__ __launch_bounds__(256) void k_agg256(
    const f16* __restrict__ sup, const int* __restrict__ rowptr,
    const int2* __restrict__ ed, const float* __restrict__ bias,
    f16* __restrict__ out, int n) {
  int wid = (blockIdx.x * THREADS + threadIdx.x) >> 6;
  int lane = threadIdx.x & 63;
  if (wid >= n) return;
  int p0 = rowptr[wid], p1 = rowptr[wid + 1];

  const f16x4* supv = (const f16x4*)sup;
  float acc[4][4] = {};
  int p = p0;
  for (; p + 16 <= p1; p += 16) {
    int2 e[16];
#pragma unroll
    for (int j = 0; j < 16; ++j) e[j] = ed[p + j];
    f16x4 v[16];
#pragma unroll
    for (int j = 0; j < 16; ++j) v[j] = supv[(size_t)e[j].x * 64 + lane];
#pragma unroll
    for (int j = 0; j < 16; ++j) {
      float wt = __int_as_float(e[j].y);
      acc[j & 3][0] += wt * (float)v[j][0];
      acc[j & 3][1] += wt * (float)v[j][1];
      acc[j & 3][2] += wt * (float)v[j][2];
      acc[j & 3][3] += wt * (float)v[j][3];
    }
  }
  for (; p + 4 <= p1; p += 4) {
    int2 e[4];
#pragma unroll
    for (int j = 0; j < 4; ++j) e[j] = ed[p + j];
    f16x4 v[4];
#pragma unroll
    for (int j = 0; j < 4; ++j) v[j] = supv[(size_t)e[j].x * 64 + lane];
#pragma unroll
    for (int j = 0; j < 4; ++j) {
      float wt = __int_as_float(e[j].y);
      acc[j][0] += wt * (float)v[j][0];
      acc[j][1] += wt * (float)v[j][1];
      acc[j][2] += wt * (float)v[j][2];
      acc[j][3] += wt * (float)v[j][3];
    }
  }
  for (; p < p1; ++p) {
    int2 e0 = ed[p];
    float wt = __int_as_float(e0.y);
    f16x4 v = supv[(size_t)e0.x * 64 + lane];
    acc[0][0] += wt * (float)v[0];
    acc[0][1] += wt * (float)v[1];
    acc[0][2] += wt * (float)v[2];
    acc[0][3] += wt * (float)v[3];
  }
  float4 b = *(const float4*)(bias + lane * 4);
  f16x4 r;
  r[0] = (f16)fmaxf(acc[0][0] + acc[1][0] + acc[2][0] + acc[3][0] + b.x, 0.f);
  r[1] = (f16)fmaxf(acc[0][1] + acc[1][1] + acc[2][1] + acc[3][1] + b.y, 0.f);
  r[2] = (f16)fmaxf(acc[0][2] + acc[1][2] + acc[2][2] + acc[3][2] + b.z, 0.f);
  r[3] = (f16)fmaxf(acc[0][3] + acc[1][3] + acc[2][3] + acc[3][3] + b.w, 0.f);
  *(f16x4*)(out + (size_t)wid * 256 + lane * 4) = r;
}

// ---------------- Aggregation D=64: one WAVE per row, 2 edges/step via half-waves ----
// lane<32 handles even edges, lane>=32 odd edges; each lane loads f16x2 (4B).
// Final __shfl_xor(32) merges the halves. 16 pair-steps = 32 edges in flight.

__global__ __launch_bounds__(256) void k_agg64(
    const f16* __restrict__ sup, const int* __restrict__ rowptr,
    const int2* __restrict__ ed, const float* __restrict__ bias,
    float* __restrict__ out, int n) {
  int wid = (blockIdx.x * THREADS + threadIdx.x) >> 6;
  int lane = threadIdx.x & 63;
  if (wid >= n) return;
  int p0 = rowptr[wid], p1 = rowptr[wid + 1];
  int half = lane >> 5;   // which edge of the pair
  int hl = lane & 31;     // col-pair index (2 cols per lane)

  const f16x2* supv = (const f16x2*)sup;  // 32 pairs per 64-wide row
  float ax = 0.f, ay = 0.f, bx = 0.f, by = 0.f;
  int p = p0;
  for (; p + 32 <= p1; p += 32) {
    int2 e[16];
#pragma unroll
    for (int j = 0; j < 16; ++j) e[j] = ed[p + 2 * j + half];
    f16x2 v[16];
#pragma unroll
    for (int j = 0; j < 16; ++j) v[j] = supv[(size_t)e[j].x * 32 + hl];
#pragma unroll
    for (int j = 0; j < 16; ++j) {
      float wt = __int_as_float(e[j].y);
      if (j & 1) { bx += wt * (float)v[j][0]; by += wt * (float)v[j][1]; }
      else       { ax += wt * (float)v[j][0]; ay += wt * (float)v[j][1]; }
    }
  }
  for (; p + 8 <= p1; p += 8) {
    int2 e[4];
#pragma unroll
    for (int j = 0; j < 4; ++j) e[j] = ed[p + 2 * j + half];
    f16x2 v[4];
#pragma unroll
    for (int j = 0; j < 4; ++j) v[j] = supv[(size_t)e[j].x * 32 + hl];
#pragma unroll
    for (int j = 0; j < 4; ++j) {
      float wt = __int_as_float(e[j].y);
      if (j & 1) { bx += wt * (float)v[j][0]; by += wt * (float)v[j][1]; }
      else       { ax += wt * (float)v[j][0]; ay += wt * (float)v[j][1]; }
    }
  }
  for (; p < p1; p += 2) {
    int idx = p + half;
    float wt = 0.f;
    int c = 0;
    if (idx < p1) {
      int2 e0 = ed[idx];
      c = e0.x;
      wt = __int_as_float(e0.y);
    }
    f16x2 v = supv[(size_t)c * 32 + hl];  // c=0 harmless when wt==0
    ax += wt * (float)v[0];
    ay += wt * (float)v[1];
  }
  float tx = ax + bx;
  float ty = ay + by;
  tx += __shfl_xor(tx, 32);
  ty += __shfl_xor(ty, 32);
  if (half == 0) {
    float2 b = *(const float2*)(bias + hl * 2);
    float2 res;
    res.x = fmaxf(tx + b.x, 0.f);
    res.y = fmaxf(ty + b.y, 0.f);
    *(float2*)(out + (size_t)wid * 64 + hl * 2) = res;
  }
}

// ---------------- BN stats ----------------

__global__ __launch_bounds__(256) void k_colstats(const f16* __restrict__ y,
                                                  float* __restrict__ sums, int n) {
  __shared__ float sh[8][256];
  int t = threadIdx.x;
  int cg = (t & 31) * 8;
  int rs = t >> 5;
  float s[8] = {}, s2[8] = {};
  for (int r = blockIdx.x * 8 + rs; r < n; r += gridDim.x * 8) {
    f16x8 v = *(const f16x8*)(y + (size_t)r * 256 + cg);
#pragma unroll
    for (int j = 0; j < 8; ++j) {
      float f = (float)v[j];
      s[j] += f;
      s2[j] += f * f;
    }
  }
#pragma unroll
  for (int j = 0; j < 8; ++j) sh[rs][cg + j] = s[j];
  __syncthreads();
  float tot = 0.f;
#pragma unroll
  for (int k = 0; k < 8; ++k) tot += sh[k][t];
  atomicAdd(&sums[t], tot);
  __syncthreads();
#pragma unroll
  for (int j = 0; j < 8; ++j) sh[rs][cg + j] = s2[j];
  __syncthreads();
  tot = 0.f;
#pragma unroll
  for (int k = 0; k < 8; ++k) tot += sh[k][t];
  atomicAdd(&sums[256 + t], tot);
}

// ---------------- launch ----------------

extern "C" void kernel_launch(void* const* d_in, const int* in_sizes, int n_in,
                              void* d_out, int out_size, void* d_ws, size_t ws_size,
                              hipStream_t stream) {
  const float* x = (const float*)d_in[0];
  const int* ei = (const int*)d_in[1];
  const float* ew = (const float*)d_in[2];
  const float* W1 = (const float*)d_in[3];
  const float* b1 = (const float*)d_in[4];
  const float* W2 = (const float*)d_in[5];
  const float* b2 = (const float*)d_in[6];
  const float* W3 = (const float*)d_in[7];
  const float* b3 = (const float*)d_in[8];
  float* out = (float*)d_out;

  const int N = in_sizes[0] / 512;  // 100000
  const int E = in_sizes[2];        // 3200000

  const int NB = (N + 255) >> BSH;
  const int NBLK = (E + EPB - 1) / EPB;
  const int scanN = NB * NBLK;

  char* p = (char*)d_ws;
  auto alloc = [&](size_t bytes) {
    void* r = (void*)p;
    p += (bytes + 255) & ~(size_t)255;
    return r;
  };
  int* rowptr = (int*)alloc((size_t)(N + 1) * 4);
  int* cnt2d = (int*)alloc((size_t)scanN * 4);
  int* off2d = (int*)alloc((size_t)(scanN + 1) * 4);
  int* bsum = (int*)alloc(4096);
  // stat block: sumsA(512) | sumsB(512) | biasRowA(256) | biasRowB(256)
  float* statZ = (float*)alloc(1536 * 4);
  float* sumsA = statZ;
  float* sumsB = statZ + 512;
  float* biasRowA = statZ + 1024;
  float* biasRowB = statZ + 1280;
  f16* Wt1 = (f16*)alloc((size_t)512 * 256 * 2);
  f16* Wt2 = (f16*)alloc((size_t)256 * 256 * 2);
  f16* Wt3 = (f16*)alloc((size_t)256 * 64 * 2);
  int2* temp = (int2*)alloc((size_t)E * 8);
  int2* ed = (int2*)alloc((size_t)E * 8);
  f16* sup = (f16*)alloc((size_t)N * 256 * 2);
  f16* act = (f16*)alloc((size_t)N * 256 * 2);

  const int* rows = ei;
  const int* colsIn = ei + E;

  // --- CSR build (atomic-free binning) ---
  k_hist<<<NBLK, 256, 0, stream>>>(rows, cnt2d, E, NBLK, NB);
  int nbs = (scanN + 1023) / 1024;
  k_scan1<<<nbs, 256, 0, stream>>>(cnt2d, off2d, bsum, scanN);
  k_scan2<<<1, 256, 0, stream>>>(bsum, nbs);
  k_scan3<<<nbs, 256, 0, stream>>>(off2d, bsum, scanN, E);
  k_bin<<<NBLK, 256, 0, stream>>>(rows, colsIn, ew, off2d, temp, E, NBLK, NB);
  k_scatter<<<NB, 256, 0, stream>>>(temp, off2d, rowptr, ed, N, E, NBLK, NB);

  const int gemmBlocks = (N + 127) / 128;
  const int aggBlocks = (N * 64 + THREADS - 1) / THREADS;

  // --- Layer 1 (convW also zeroes sumsA/sumsB/biasRowA/biasRowB) ---
  k_convW<<<(512 * 256 + THREADS - 1) / THREADS, THREADS, 0, stream>>>(W1, Wt1, 512, 256, statZ);
  k_gemm_mfma<256, false><<<gemmBlocks, 256, 0, stream>>>(x, Wt1, nullptr, sup, N, 512);
  k_agg256<<<aggBlocks, 256, 0, stream>>>(sup, rowptr, ed, b1, act, N);

  // --- BN1 + fold into W2 ---
  k_colstats<<<240, 256, 0, stream>>>(act, sumsA, N);
  k_bnfold<<<(256 * 256 + 255) / 256, 256, 0, stream>>>(W2, sumsA, Wt2, biasRowA, 256, 256, N);

  // --- Layer 2 ---
  k_gemm_mfma<256, true><<<gemmBlocks, 256, 0, stream>>>(act, Wt2, biasRowA, sup, N, 256);
  k_agg256<<<aggBlocks, 256, 0, stream>>>(sup, rowptr, ed, b2, act, N);

  // --- BN2 + fold into W3 ---
  k_colstats<<<240, 256, 0, stream>>>(act, sumsB, N);
  k_bnfold<<<(256 * 64 + 255) / 256, 256, 0, stream>>>(W3, sumsB, Wt3, biasRowB, 256, 64, N);

  // --- Layer 3 ---
  k_gemm_mfma<64, true><<<gemmBlocks, 256, 0, stream>>>(act, Wt3, biasRowB, sup, N, 256);
  k_agg64<<<aggBlocks, 256, 0, stream>>>(sup, rowptr, ed, b3, out, N);
}